// Round 5
// baseline (245.604 us; speedup 1.0000x reference)
//
#include <hip/hip_runtime.h>
#include <stdint.h>

// Problem constants
#define DIM    1024
#define RANK   16
#define M_TOT  8192          // 2*4096 rows of x
#define N_TOT  3072          // 3*DIM output features
#define K_TOT  1024

// GEMM tiling: block = 256x128, BK=64, 8 waves (4M x 2N), wave tile 64x64
#define BM 256
#define BN 128
#define BK 64
#define NT (K_TOT / BK)      // 16 K-tiles

typedef __attribute__((ext_vector_type(8))) short  s8v;   // 8 x bf16 (raw bits)
typedef __attribute__((ext_vector_type(4))) float  f4v;   // MFMA acc

__device__ __forceinline__ unsigned short f2bf(float f) {
    union { float f; unsigned int u; } v; v.f = f;
    unsigned int u = v.u;
    u += 0x7FFFu + ((u >> 16) & 1u);   // round-to-nearest-even
    return (unsigned short)(u >> 16);
}

// Async global->LDS DMA, 16 B/lane. LDS dest is wave-uniform base + lane*16;
// global src carries the fragment swizzle (m173 pattern).
__device__ __forceinline__ void gload_lds16(const unsigned short* g,
                                            unsigned short* l) {
    __builtin_amdgcn_global_load_lds(
        (const __attribute__((address_space(1))) void*)g,
        (__attribute__((address_space(3))) void*)l,
        16, 0, 0);
}

// ---------------- Kernel 1: fused prep (unchanged from round 3) ----------------
__global__ __launch_bounds__(256)
void prep(const float4* __restrict__ x, ushort4* __restrict__ xb,
          const float* __restrict__ W,
          const float* __restrict__ Aq, const float* __restrict__ Bq,
          const float* __restrict__ Ak, const float* __restrict__ Bk,
          const float* __restrict__ Av, const float* __restrict__ Bv,
          const float* __restrict__ alpha_p,
          unsigned short* __restrict__ Wb) {
    const int tid = threadIdx.x;
    if (blockIdx.x < 2048) {
        int i = blockIdx.x * 256 + tid;          // 2048*256*4 = 2097152 exact
        #pragma unroll
        for (int k = 0; k < 4; ++k) {
            float4 v = x[i];
            ushort4 o;
            o.x = f2bf(v.x); o.y = f2bf(v.y); o.z = f2bf(v.z); o.w = f2bf(v.w);
            xb[i] = o;
            i += 2048 * 256;
        }
    } else {
        const int bid2 = blockIdx.x - 2048;      // 0..191
        const int sel  = bid2 >> 6;              // 0=q 1=k 2=v
        const int rb   = bid2 & 63;              // rows rb*16..+16
        const float* Am = (sel == 0) ? Aq : (sel == 1) ? Ak : Av;  // [RANK, DIM]
        const float* Bm = (sel == 0) ? Bq : (sel == 1) ? Bk : Bv;  // [DIM, RANK]

        __shared__ float sb[16][RANK];
        {
            const int row = rb * 16 + (tid >> 4);
            sb[tid >> 4][tid & 15] = alpha_p[0] * Bm[row * RANK + (tid & 15)];
        }
        __syncthreads();

        float4 a4[RANK];                          // A column-slice, 64 VGPRs
        #pragma unroll
        for (int r = 0; r < RANK; ++r)
            a4[r] = ((const float4*)(Am + r * DIM))[tid];

        #pragma unroll
        for (int row = 0; row < 16; ++row) {
            const int o = sel * 1024 + rb * 16 + row;
            float4 w = ((const float4*)(W + (size_t)o * DIM))[tid];
            #pragma unroll
            for (int r = 0; r < RANK; ++r) {
                const float s = sb[row][r];
                w.x += s * a4[r].x; w.y += s * a4[r].y;
                w.z += s * a4[r].z; w.w += s * a4[r].w;
            }
            ushort4 ov;
            ov.x = f2bf(w.x); ov.y = f2bf(w.y); ov.z = f2bf(w.z); ov.w = f2bf(w.w);
            ((ushort4*)(Wb + (size_t)o * DIM))[tid] = ov;
        }
    }
}

// ---------------- Kernel 2: bf16 MFMA GEMM, C = Xb * Wb^T + bias ----------------
// Ring-3 phase pipeline, m201 fencing discipline:
//   - FULLY UNROLLED quad loop: ring slots, DMA predicates, tail waits all
//     compile-time constant; compiler can schedule across phase boundaries.
//   - sched_barrier(0) ONLY where required: after each lgkmcnt(0) (rule #18)
//     and sandwiching the end-of-quad barrier (the one barrier with a
//     cross-quad slot-reuse hazard). Mid-quad barriers are unfenced -- the
//     compute slot is stable all quad and DMA targets a different slot, so
//     the compiler may float next-phase reads/addr-calc into the MFMA drain
//     window (the overlap round 4's fences forbade; cf. m141 regression).
//   - counted vmcnt(6) once per quad, never 0 until the tail (T4).
//   - setprio(1) around each MFMA cluster (T5).
// XCD mapping: per-concurrent-round chunk = 4 bm x 8 bn -> A-slab 2 MB +
// B-panel 2 MB = one 4 MB L2. A stripe is XCD-fixed (resident across all 3
// chunks); only B (2 MB) refills per chunk -> ~8 MB L2-fill per XCD total.
__global__ __launch_bounds__(512, 2)
void gemm_bt(const unsigned short* __restrict__ Xb,
             const unsigned short* __restrict__ Wb,
             const float* __restrict__ bias,
             float* __restrict__ out) {
    __shared__ __align__(16) unsigned short As[3][BM * BK];  // 3 x 32 KB
    __shared__ __align__(16) unsigned short Bs[3][BN * BK];  // 3 x 16 KB

    const int tid  = threadIdx.x;
    const int wave = tid >> 6;       // 0..7
    const int lane = tid & 63;
    const int l15  = lane & 15;
    const int lq   = lane >> 4;      // 0..3
    const int wr   = wave >> 1;      // M quadrant 0..3 (64 rows each)
    const int wc   = wave & 1;       // N half     0..1 (64 cols each)

    // Bijective: xcd 0..7 x chunk 0..2 x t 0..31 -> (bm,bn) covers 32x24 once.
    const int bid   = blockIdx.x;
    const int xcd   = bid & 7;       // gfx950 round-robins blockIdx over XCDs (m09)
    const int s     = bid >> 3;      // 0..95, dispatch-sequential within XCD
    const int chunk = s >> 5;        // 0..2  (32 blocks = one concurrent XCD round)
    const int t5    = s & 31;
    const int bm    = xcd * 4 + (t5 >> 3);   // XCD-fixed A stripe (2 MB, L2-resident)
    const int bn    = chunk * 8 + (t5 & 7);  // per-chunk B panel (2 MB, L2-resident)

    // Staging: A = 32 chunks of 1 KB, wave w owns chunks w*4..+3.
    //          B = 16 chunks, wave w owns chunks w*2..+1.
    // Chunk c: rows (c>>1)*16 + l15, k-cols (c&1)*32 + lq*8 (8 halves/lane).
    // LDS chunk c = wave-uniform base c*1024B + lane*16B (linear DMA order).
    const unsigned short* aptr[4];
    const unsigned short* bptr[2];
    int aoff[4], boff[2];
    #pragma unroll
    for (int u = 0; u < 4; ++u) {
        const int c   = wave * 4 + u;                // 0..31
        const int row = ((c >> 1) << 4) + l15;       // 0..255
        const int col = ((c & 1) << 5) + (lq << 3);  // 0..56
        aptr[u] = Xb + (size_t)(bm * BM + row) * K_TOT + col;
        aoff[u] = c * 512;
    }
    #pragma unroll
    for (int u = 0; u < 2; ++u) {
        const int c   = wave * 2 + u;                // 0..15
        const int row = ((c >> 1) << 4) + l15;       // 0..127
        const int col = ((c & 1) << 5) + (lq << 3);
        bptr[u] = Wb + (size_t)(bn * BN + row) * K_TOT + col;
        boff[u] = c * 512;
    }

    // Prologue: tiles 0,1 -> slots 0,1 (12 loads/wave); tile 0 resident,
    // tile 1's 6 stay in flight.
    #pragma unroll
    for (int t = 0; t < 2; ++t) {
        #pragma unroll
        for (int u = 0; u < 4; ++u) gload_lds16(aptr[u] + t * BK, &As[t][aoff[u]]);
        #pragma unroll
        for (int u = 0; u < 2; ++u) gload_lds16(bptr[u] + t * BK, &Bs[t][boff[u]]);
    }
    asm volatile("s_waitcnt vmcnt(6)" ::: "memory");
    __builtin_amdgcn_sched_barrier(0);
    __builtin_amdgcn_s_barrier();
    __builtin_amdgcn_sched_barrier(0);

    f4v acc[4][4] = {};

    #pragma unroll
    for (int q = 0; q < NT; ++q) {           // FULL unroll: all indices static
        const int r    = q % 3;              // compute slot (tile q)
        const int r2   = (q + 2) % 3;        // DMA target slot (tile q+2)
        const int kg   = (q + 2) * BK;
        const bool iss = (q + 2) < NT;

        const s8v* Avp = (const s8v*)As[r];
        const s8v* Bvp = (const s8v*)Bs[r];

        #pragma unroll
        for (int t = 0; t < 2; ++t) {        // phase A (t=0), phase B (t=1)
            s8v af[4], bf[4];
            #pragma unroll
            for (int i = 0; i < 4; ++i) {
                af[i] = Avp[((wr * 4 + i) * 2 + t) * 64 + lane];
                bf[i] = Bvp[((wc * 4 + i) * 2 + t) * 64 + lane];
            }
            if (iss) {                       // 3 of tile q+2's 6 loads per phase
                if (t == 0) {
                    gload_lds16(aptr[0] + kg, &As[r2][aoff[0]]);
                    gload_lds16(aptr[1] + kg, &As[r2][aoff[1]]);
                    gload_lds16(bptr[0] + kg, &Bs[r2][boff[0]]);
                } else {
                    gload_lds16(aptr[2] + kg, &As[r2][aoff[2]]);
                    gload_lds16(aptr[3] + kg, &As[r2][aoff[3]]);
                    gload_lds16(bptr[1] + kg, &Bs[r2][boff[1]]);
                }
            }
            __builtin_amdgcn_s_barrier();    // unfenced: no slot hazard mid-quad
            asm volatile("s_waitcnt lgkmcnt(0)" ::: "memory");
            __builtin_amdgcn_sched_barrier(0);           // rule #18
            __builtin_amdgcn_s_setprio(1);
            #pragma unroll
            for (int i = 0; i < 4; ++i)
                #pragma unroll
                for (int j = 0; j < 4; ++j)
                    acc[i][j] = __builtin_amdgcn_mfma_f32_16x16x32_bf16(
                        af[i], bf[j], acc[i][j], 0, 0, 0);
            __builtin_amdgcn_s_setprio(0);

            if (t == 0) {
                __builtin_amdgcn_s_barrier();            // unfenced mid-quad close
            } else {
                // End-of-quad: tile q+1 must be resident for next quad's reads;
                // tile q+2's 6 loads stay in flight (counted, never 0 mid-loop).
                if (q < NT - 2)
                    asm volatile("s_waitcnt vmcnt(6)" ::: "memory");
                else if (q == NT - 2)
                    asm volatile("s_waitcnt vmcnt(0)" ::: "memory");
                if (q < NT - 1) {
                    // Fenced: next quad's DMA overwrites slot (q+3)%3 == r,
                    // the slot read this quad -- reads must stay above, DMA below.
                    __builtin_amdgcn_sched_barrier(0);
                    __builtin_amdgcn_s_barrier();
                    __builtin_amdgcn_sched_barrier(0);
                }
            }
        }
    }

    // Epilogue: C/D layout col = lane&15, row = (lane>>4)*4 + reg  [m89]
    const int col_base = bn * BN + wc * 64;
    const int row_base = bm * BM + wr * 64 + lq * 4;
    #pragma unroll
    for (int j = 0; j < 4; ++j) {
        const int col = col_base + j * 16 + l15;
        const float bv = bias[col];
        #pragma unroll
        for (int i = 0; i < 4; ++i) {
            const int row = row_base + i * 16;
            #pragma unroll
            for (int r = 0; r < 4; ++r)
                out[(size_t)(row + r) * N_TOT + col] = acc[i][j][r] + bv;
        }
    }
}

extern "C" void kernel_launch(void* const* d_in, const int* in_sizes, int n_in,
                              void* d_out, int out_size, void* d_ws, size_t ws_size,
                              hipStream_t stream) {
    const float* x     = (const float*)d_in[0];   // [2,4096,1024]
    const float* W     = (const float*)d_in[1];   // [3072,1024]
    const float* b     = (const float*)d_in[2];   // [3072]
    const float* Aq    = (const float*)d_in[3];
    const float* Bq    = (const float*)d_in[4];
    const float* Ak    = (const float*)d_in[5];
    const float* Bk    = (const float*)d_in[6];
    const float* Av    = (const float*)d_in[7];
    const float* Bv    = (const float*)d_in[8];
    const float* alpha = (const float*)d_in[9];
    float* out = (float*)d_out;

    unsigned short* xb = (unsigned short*)d_ws;                                      // 16 MB
    unsigned short* Wb = (unsigned short*)((char*)d_ws + (size_t)M_TOT * K_TOT * 2); // +6 MB

    prep<<<2048 + 192, 256, 0, stream>>>((const float4*)x, (ushort4*)xb,
                                         W, Aq, Bq, Ak, Bk, Av, Bv, alpha, Wb);

    // 32 M-tiles x 24 N-tiles = 768 blocks = exactly 3 rounds of 256 CUs
    gemm_bt<<<(M_TOT / BM) * (N_TOT / BN), 512, 0, stream>>>(xb, Wb, b, out);
}

// Round 6
// 225.805 us; speedup vs baseline: 1.0877x; 1.0877x over previous
//
#include <hip/hip_runtime.h>
#include <stdint.h>

// Problem constants
#define DIM    1024
#define RANK   16
#define M_TOT  8192          // 2*4096 rows of x
#define N_TOT  3072          // 3*DIM output features
#define K_TOT  1024

// GEMM tiling: block = 256x256, BK=32, 8 waves (2M x 4N), wave tile 128x64
#define BM 256
#define BN 256
#define BK 32
#define NT (K_TOT / BK)      // 32 K-tiles
// LDS ring: 4 slots x 32 KB (A 16 KB + B 16 KB) = 128 KB
#define SLOT_H   16384       // halves per slot
#define SLOT_V   2048        // s8v per slot
#define B_OFF_H  8192        // B region offset (halves)
#define B_OFF_V  1024        // B region offset (s8v)

typedef __attribute__((ext_vector_type(8))) short  s8v;   // 8 x bf16 (raw bits)
typedef __attribute__((ext_vector_type(4))) float  f4v;   // MFMA acc

__device__ __forceinline__ unsigned short f2bf(float f) {
    union { float f; unsigned int u; } v; v.f = f;
    unsigned int u = v.u;
    u += 0x7FFFu + ((u >> 16) & 1u);   // round-to-nearest-even
    return (unsigned short)(u >> 16);
}

// Async global->LDS DMA, 16 B/lane. LDS dest is wave-uniform base + lane*16;
// global src carries the fragment swizzle (m173 pattern).
__device__ __forceinline__ void gload_lds16(const unsigned short* g,
                                            unsigned short* l) {
    __builtin_amdgcn_global_load_lds(
        (const __attribute__((address_space(1))) void*)g,
        (__attribute__((address_space(3))) void*)l,
        16, 0, 0);
}

// ---------------- Kernel 1: fused prep (unchanged from round 3) ----------------
__global__ __launch_bounds__(256)
void prep(const float4* __restrict__ x, ushort4* __restrict__ xb,
          const float* __restrict__ W,
          const float* __restrict__ Aq, const float* __restrict__ Bq,
          const float* __restrict__ Ak, const float* __restrict__ Bk,
          const float* __restrict__ Av, const float* __restrict__ Bv,
          const float* __restrict__ alpha_p,
          unsigned short* __restrict__ Wb) {
    const int tid = threadIdx.x;
    if (blockIdx.x < 2048) {
        int i = blockIdx.x * 256 + tid;          // 2048*256*4 = 2097152 exact
        #pragma unroll
        for (int k = 0; k < 4; ++k) {
            float4 v = x[i];
            ushort4 o;
            o.x = f2bf(v.x); o.y = f2bf(v.y); o.z = f2bf(v.z); o.w = f2bf(v.w);
            xb[i] = o;
            i += 2048 * 256;
        }
    } else {
        const int bid2 = blockIdx.x - 2048;      // 0..191
        const int sel  = bid2 >> 6;              // 0=q 1=k 2=v
        const int rb   = bid2 & 63;              // rows rb*16..+16
        const float* Am = (sel == 0) ? Aq : (sel == 1) ? Ak : Av;  // [RANK, DIM]
        const float* Bm = (sel == 0) ? Bq : (sel == 1) ? Bk : Bv;  // [DIM, RANK]

        __shared__ float sb[16][RANK];
        {
            const int row = rb * 16 + (tid >> 4);
            sb[tid >> 4][tid & 15] = alpha_p[0] * Bm[row * RANK + (tid & 15)];
        }
        __syncthreads();

        float4 a4[RANK];                          // A column-slice, 64 VGPRs
        #pragma unroll
        for (int r = 0; r < RANK; ++r)
            a4[r] = ((const float4*)(Am + r * DIM))[tid];

        #pragma unroll
        for (int row = 0; row < 16; ++row) {
            const int o = sel * 1024 + rb * 16 + row;
            float4 w = ((const float4*)(W + (size_t)o * DIM))[tid];
            #pragma unroll
            for (int r = 0; r < RANK; ++r) {
                const float s = sb[row][r];
                w.x += s * a4[r].x; w.y += s * a4[r].y;
                w.z += s * a4[r].z; w.w += s * a4[r].w;
            }
            ushort4 ov;
            ov.x = f2bf(w.x); ov.y = f2bf(w.y); ov.z = f2bf(w.z); ov.w = f2bf(w.w);
            ((ushort4*)(Wb + (size_t)o * DIM))[tid] = ov;
        }
    }
}

// ---------------- Kernel 2: bf16 MFMA GEMM, C = Xb * Wb^T + bias ----------------
// Ring-4, ONE barrier per K-tile:
//   Because each tile has 2 full quads of slack (issued at quad q-3, waited at
//   quad q-1's end), slot q%4 is vmcnt-confirmed and barrier-published before
//   quad q begins and is stable all quad -> no intra-quad sync at all. Per
//   quad: {issue tile q+3's 4 DMA -> 12 ds_read_b128 -> 32 MFMA (setprio)} then
//   [sched_barrier; vmcnt(8) counted; s_barrier; sched_barrier]. The fence
//   sandwich is the ONLY pinning point (r4-vs-r5 evidence: fence the hazard,
//   free the rest); it also keeps MFMAs+their lgkm waits above the barrier so
//   next quad's DMA can't clobber an in-flight ds_read (rule #18 analog).
//   vmcnt(8) = tiles q+2 (4) + q+3 (4) stay in flight; never 0 until tail (T4).
// Geometry doubles arithmetic intensity vs rounds 2-5 (256^2 output per 32KB
// staged K-tile): per-CU L2-delivery floor halves; m230/m248 show 256^2 tiles
// reach 655-848 TF at K=1024 where 2-phase 256x128 capped at ~530.
__global__ __launch_bounds__(512, 2)
void gemm_bt(const unsigned short* __restrict__ Xb,
             const unsigned short* __restrict__ Wb,
             const float* __restrict__ bias,
             float* __restrict__ out) {
    __shared__ __align__(16) unsigned short S[4 * SLOT_H];   // 128 KB ring

    const int tid  = threadIdx.x;
    const int wave = tid >> 6;       // 0..7
    const int lane = tid & 63;
    const int l15  = lane & 15;
    const int lq   = lane >> 4;      // 0..3
    const int wr   = wave >> 2;      // M half    0..1 (128 rows)
    const int wc   = wave & 3;       // N quarter 0..3 (64 cols)

    // XCD map (r5-proven, FETCH 86->49 MB): per XCD a 4bm x 12bn chunk;
    // A-stripe (4x256 rows = 2 MB) L2-resident, B (6 MB) streams via L3.
    // Bijective: xcd 0..7, s 0..47 -> bm = xcd*4 + s/12 (0..31), bn = s%12.
    const int bid = blockIdx.x;
    const int xcd = bid & 7;
    const int s   = bid >> 3;        // 0..47
    const int bm  = xcd * 4 + s / 12;
    const int bn  = s % 12;

    // Staging: per K-tile, A = 16 chunks of 1 KB (16 rows x 32 k), B = 16.
    // Wave w owns A chunks {2w, 2w+1} and B chunks {2w, 2w+1} -> 4 loads/quad.
    // Chunk c: rows c*16 + l15, k-cols lq*8 (8 halves/lane). LDS chunk c =
    // wave-uniform base + lane*16B  (linear DMA order; internal layout
    // identical to rounds 0-5's verified fragment chunks).
    const unsigned short* aptr[2];
    const unsigned short* bptr[2];
    int aoff[2], boff[2];            // chunk bases (halves) within a slot
    #pragma unroll
    for (int u = 0; u < 2; ++u) {
        const int c   = wave * 2 + u;            // 0..15
        const int row = c * 16 + l15;            // 0..255
        const int col = lq << 3;                 // 0..24
        aptr[u] = Xb + (size_t)(bm * BM + row) * K_TOT + col;
        bptr[u] = Wb + (size_t)(bn * BN + row) * K_TOT + col;
        aoff[u] = c * 512;
        boff[u] = B_OFF_H + c * 512;
    }

    #define STAGE(q)                                                         \
    {                                                                        \
        unsigned short* sl = &S[((q) & 3) * SLOT_H];                         \
        const int kk = (q) * BK;                                             \
        gload_lds16(aptr[0] + kk, sl + aoff[0]);                             \
        gload_lds16(aptr[1] + kk, sl + aoff[1]);                             \
        gload_lds16(bptr[0] + kk, sl + boff[0]);                             \
        gload_lds16(bptr[1] + kk, sl + boff[1]);                             \
    }

    f4v acc[8][4] = {};

    #define COMPUTE(q)                                                       \
    {                                                                        \
        const s8v* P = (const s8v*)S + ((q) & 3) * SLOT_V;                   \
        s8v af[8], bf[4];                                                    \
        _Pragma("unroll")                                                    \
        for (int j = 0; j < 4; ++j)                                          \
            bf[j] = P[B_OFF_V + (wc * 4 + j) * 64 + lane];                   \
        _Pragma("unroll")                                                    \
        for (int i = 0; i < 8; ++i)                                          \
            af[i] = P[(wr * 8 + i) * 64 + lane];                             \
        __builtin_amdgcn_s_setprio(1);                                       \
        _Pragma("unroll")                                                    \
        for (int i = 0; i < 8; ++i)                                          \
            _Pragma("unroll")                                                \
            for (int j = 0; j < 4; ++j)                                      \
                acc[i][j] = __builtin_amdgcn_mfma_f32_16x16x32_bf16(         \
                    af[i], bf[j], acc[i][j], 0, 0, 0);                       \
        __builtin_amdgcn_s_setprio(0);                                       \
    }

    // Quad-boundary sync: the ONLY hazard point (next quad's DMA overwrites
    // the slot just read). Fenced so no MFMA/ds_read leaks past it.
    #define QSYNC(n)                                                         \
    {                                                                        \
        __builtin_amdgcn_sched_barrier(0);                                   \
        asm volatile("s_waitcnt vmcnt(" #n ")" ::: "memory");                \
        __builtin_amdgcn_s_barrier();                                        \
        __builtin_amdgcn_sched_barrier(0);                                   \
    }

    // Prologue: tiles 0,1,2 in flight (12 loads/wave); tile 0 resident after
    // vmcnt(8); tiles 1,2 stay in flight.
    STAGE(0); STAGE(1); STAGE(2);
    QSYNC(8);

    // Main loop: q = 0..NT-5 (28 iters, unroll 4 -> slot indices static).
    // Invariant entering quad q: tile q resident+published; q+1,q+2 in flight.
    #pragma unroll 4
    for (int q = 0; q < NT - 4; ++q) {
        STAGE(q + 3);          // issue first: 2 quads of slack for tile q+3
        COMPUTE(q);
        QSYNC(8);              // tile q+1 lands; q+2,q+3 stay in flight
    }
    // Tail: q = NT-4 .. NT-1 (28..31), last STAGE at q=28 (tile 31).
    STAGE(NT - 1);
    COMPUTE(NT - 4);
    QSYNC(8);                  // tile 29 lands; 30,31 in flight
    COMPUTE(NT - 3);
    QSYNC(4);                  // tile 30 lands; 31 in flight
    COMPUTE(NT - 2);
    QSYNC(0);                  // tile 31 lands
    COMPUTE(NT - 1);
    #undef STAGE
    #undef COMPUTE
    #undef QSYNC

    // Epilogue: C/D layout col = lane&15, row = (lane>>4)*4 + reg  [m89]
    const int col_base = bn * BN + wc * 64;
    const int row_base = bm * BM + wr * 128 + lq * 4;
    #pragma unroll
    for (int j = 0; j < 4; ++j) {
        const int col = col_base + j * 16 + l15;
        const float bv = bias[col];
        #pragma unroll
        for (int i = 0; i < 8; ++i) {
            const int row = row_base + i * 16;
            #pragma unroll
            for (int r = 0; r < 4; ++r)
                out[(size_t)(row + r) * N_TOT + col] = acc[i][j][r] + bv;
        }
    }
}

extern "C" void kernel_launch(void* const* d_in, const int* in_sizes, int n_in,
                              void* d_out, int out_size, void* d_ws, size_t ws_size,
                              hipStream_t stream) {
    const float* x     = (const float*)d_in[0];   // [2,4096,1024]
    const float* W     = (const float*)d_in[1];   // [3072,1024]
    const float* b     = (const float*)d_in[2];   // [3072]
    const float* Aq    = (const float*)d_in[3];
    const float* Bq    = (const float*)d_in[4];
    const float* Ak    = (const float*)d_in[5];
    const float* Bk    = (const float*)d_in[6];
    const float* Av    = (const float*)d_in[7];
    const float* Bv    = (const float*)d_in[8];
    const float* alpha = (const float*)d_in[9];
    float* out = (float*)d_out;

    unsigned short* xb = (unsigned short*)d_ws;                                      // 16 MB
    unsigned short* Wb = (unsigned short*)((char*)d_ws + (size_t)M_TOT * K_TOT * 2); // +6 MB

    prep<<<2048 + 192, 256, 0, stream>>>((const float4*)x, (ushort4*)xb,
                                         W, Aq, Bq, Ak, Bk, Av, Bv, alpha, Wb);

    // 32 M-tiles x 12 N-tiles = 384 blocks (1.5 rounds of 256 CUs)
    gemm_bt<<<(M_TOT / BM) * (N_TOT / BN), 512, 0, stream>>>(xb, Wb, b, out);
}